// Round 2
// baseline (13404.639 us; speedup 1.0000x reference)
//
#include <hip/hip_runtime.h>

typedef unsigned short u16;
typedef unsigned int   u32;
typedef short short8 __attribute__((ext_vector_type(8)));
typedef float f32x4  __attribute__((ext_vector_type(4)));
typedef u32   u32x4  __attribute__((ext_vector_type(4)));

#define AGENT __HIP_MEMORY_SCOPE_AGENT

// ---------- bf16 helpers (raw-bit, RNE) ----------
__device__ __forceinline__ float bf2f(u16 u) {
    u32 x = ((u32)u) << 16;
    return __builtin_bit_cast(float, x);
}
__device__ __forceinline__ u16 f2bf(float f) {
    u32 x = __builtin_bit_cast(u32, f);
    u32 r = (x + 0x7FFFu + ((x >> 16) & 1u)) >> 16;
    return (u16)r;
}
__device__ __forceinline__ float sigmoidf_(float x) { return 1.0f / (1.0f + __expf(-x)); }
__device__ __forceinline__ float tanhf_(float x) { return 2.0f / (1.0f + __expf(-2.0f * x)) - 1.0f; }

// ---------- XCD-local (no sc1) primitives: valid ONLY when all parties share an XCD ----------
// Loads use sc0 (bypass per-CU L1, served by the XCD L2); atomics carry no sc bits
// (executed at the local TCC). Cross-XCD visibility is NOT provided — the claim
// logic below verifies co-location and falls back to agent-scope ops otherwise.
__device__ __forceinline__ int xcd_load_i32(const int* p) {
    int v;
    asm volatile("global_load_dword %0, %1, off sc0\n\t"
                 "s_waitcnt vmcnt(0)"
                 : "=v"(v) : "v"(p) : "memory");
    return v;
}
__device__ __forceinline__ void xcd_atomic_add(int* p, int v) {
    asm volatile("global_atomic_add %0, %1, off" :: "v"(p), "v"(v) : "memory");
}
__device__ __forceinline__ void xcd_load_32B(const void* p, u32* hv) {
    u32x4 a, b;
    asm volatile("global_load_dwordx4 %0, %2, off sc0\n\t"
                 "global_load_dwordx4 %1, %2, off offset:16 sc0\n\t"
                 "s_waitcnt vmcnt(0)"
                 : "=&v"(a), "=&v"(b) : "v"(p) : "memory");
    hv[0] = a.x; hv[1] = a.y; hv[2] = a.z; hv[3] = a.w;
    hv[4] = b.x; hv[5] = b.y; hv[6] = b.z; hv[7] = b.w;
}

// =====================================================================
// init: zero the 512-int control block; detect input dtype from x's raw
// bits (fp32 mantissa halves look like huge bf16 exponents ~45% of the
// time; genuine bf16 N(0,1) data: never). Single block so the zeroing
// and the flag write are race-free.
// int layout (after 64KB hbuf):
//   [0] flag | [1] backup-seq | [8..15] xcd slots | [16..31] claimed
//   [32..47] claimant xcd | [48..51] group verdict | [64..319] sync ctr
//   (group g's monotonic counter at 64 + g*64 -> private 128B line)
// =====================================================================
__global__ __launch_bounds__(256) void lstm_init(const u16* __restrict__ xbits,
                                                 int* __restrict__ ints) {
    int t = threadIdx.x;
    ints[t] = 0;
    ints[t + 256] = 0;
    if (t == 0) {
        int cnt = 0;
        const uint4* p = (const uint4*)xbits;
        for (int j = 0; j < 64; j++) {  // first 1024 u16 of x
            uint4 v = p[j];
            u32 wv[4] = {v.x, v.y, v.z, v.w};
#pragma unroll
            for (int k2 = 0; k2 < 4; k2++) {
                u32 lo = wv[k2] & 0xFFFFu, hi = wv[k2] >> 16;
                cnt += ((lo & 0x7F80u) >= 0x4600u) ? 1 : 0;
                cnt += ((hi & 0x7F80u) >= 0x4600u) ? 1 : 0;
            }
        }
        ints[0] = cnt;  // fp32 -> ~230, bf16 -> 0
    }
}

// =====================================================================
// Fused persistent LSTM. 4 batch-groups x 4 hcol-groups; the 4 WGs of a
// group are pinned to ONE XCD (runtime XCC_ID claim, grid 256 = 1
// block/CU so every XCD hosts >=4 blocks; surplus blocks exit). h
// exchange + arrival counter ride the XCD-local L2 (sc0 loads, no-sc
// atomics) instead of the device coherence point. hbuf is group-private
// ([g][par][hc][b16]) so no line is dirtied by two XCDs. If placement
// can't be verified, the group falls back to agent-scope ops (slow but
// correct). All spins are guard-bounded with a permanent dead-latch:
// worst case ~0.5 s then free-run (wrong output, but no harness hang).
// =====================================================================
__global__ __launch_bounds__(256, 1) void lstm_fused(const void* __restrict__ x,
                                                     const void* __restrict__ Wx,
                                                     const void* __restrict__ Wh,
                                                     const void* __restrict__ bias,
                                                     const void* __restrict__ c0,
                                                     const void* __restrict__ h0,
                                                     u16* __restrict__ hbuf,
                                                     void* __restrict__ out,
                                                     int* __restrict__ ints) {
    __shared__ __align__(16) u16 hs[16 * 264];  // [m 0..15][k 0..255 +pad]; also W transpose scratch
    __shared__ int sb[3];

    const int tid = threadIdx.x;
    const int lane = tid & 63, w = tid >> 6;
    const int q = lane >> 4, n16 = lane & 15;

    // ---- work assignment: claim (group, member) with co-XCD placement ----
    if (tid == 0) {
        int* xslots  = ints + 8;
        int* claimed = ints + 16;   // 0 free, 1 primary, 2 backup
        int* mxcd    = ints + 32;
        int* okv     = ints + 48;   // 0 pending, 1 fast(L2-local), 2 slow(agent)
        int xcd = __builtin_amdgcn_s_getreg((3u << 11) | 20) & 7;  // HW_REG_XCC_ID
        int g = -1, mm = -1;
        int slot = __hip_atomic_fetch_add(&xslots[xcd], 1, __ATOMIC_RELAXED, AGENT);
        if (xcd < 4 && slot < 4) {
            int id = xcd * 4 + slot;
            __hip_atomic_store(&mxcd[id], xcd, __ATOMIC_RELEASE, AGENT);
            int exp0 = 0;
            if (__hip_atomic_compare_exchange_strong(&claimed[id], &exp0, 1,
                    __ATOMIC_ACQ_REL, __ATOMIC_RELAXED, AGENT)) { g = xcd; mm = slot; }
        } else {
            // backup path: only engages if an XCD failed to field 4 primaries
            int seq = __hip_atomic_fetch_add(&ints[1], 1, __ATOMIC_RELAXED, AGENT);
            if (seq < 16) {
                int seen = 0;
                for (int it = 0; it < 4096; ++it) {
                    if (__hip_atomic_load(&claimed[seq], __ATOMIC_RELAXED, AGENT)) { seen = 1; break; }
                    __builtin_amdgcn_s_sleep(32);
                }
                if (!seen) {
                    __hip_atomic_store(&mxcd[seq], 64, __ATOMIC_RELEASE, AGENT);  // 64: never matches -> slow
                    int exp0 = 0;
                    if (__hip_atomic_compare_exchange_strong(&claimed[seq], &exp0, 2,
                            __ATOMIC_ACQ_REL, __ATOMIC_RELAXED, AGENT)) { g = seq >> 2; mm = seq & 3; }
                }
            }
        }
        int fast = 0;
        if (g >= 0) {
            if (mm == 0) {
                // member 0 renders the group's verdict so all members agree
                int all = 1;
                for (int k = 1; k < 4; ++k) {
                    int it = 0;
                    while (!__hip_atomic_load(&claimed[g * 4 + k], __ATOMIC_ACQUIRE, AGENT)) {
                        __builtin_amdgcn_s_sleep(16);
                        if (++it > (1 << 19)) { all = 0; break; }
                    }
                }
                int myx = __hip_atomic_load(&mxcd[g * 4 + 0], __ATOMIC_RELAXED, AGENT);
                if (all) {
                    fast = 1;
                    for (int k = 1; k < 4; ++k)
                        if (__hip_atomic_load(&mxcd[g * 4 + k], __ATOMIC_RELAXED, AGENT) != myx) fast = 0;
                }
                __hip_atomic_store(&okv[g], fast ? 1 : 2, __ATOMIC_RELEASE, AGENT);
            }
            int it = 0, o;
            while ((o = __hip_atomic_load(&okv[g], __ATOMIC_ACQUIRE, AGENT)) == 0) {
                __builtin_amdgcn_s_sleep(16);
                if (++it > (1 << 20)) { o = 2; break; }
            }
            fast = (o == 1);
        }
        sb[0] = g; sb[1] = mm; sb[2] = fast;
    }
    __syncthreads();
    const int jB = sb[0], jH = sb[1], fast = sb[2];
    if (jB < 0) return;  // surplus block

    const int b0 = jB * 16;
    const int hc = jH * 64 + w * 16 + n16;  // this lane's h column
    const int bq = b0 + q * 4;              // first of 4 batch rows for this lane

    const int isf32 = (ints[0] > 64);       // wave-uniform runtime dtype switch
    int* const ctrp = ints + 64 + jB * 64;  // group's hot (L2-resident) arrival counter
    u16* const hgrp = hbuf + (size_t)jB * 8192;  // group-private: [par 2][hc 256][b16]

    // ---- preload Wh and Wx B-fragments into registers via LDS piece transpose ----
    short8 Bh[4][8];  // [gate][k-step]; 128 VGPRs
    short8 Bx[4][8];  // 128 VGPRs

#define PRELOAD_W(Wsrc, Bf)                                                    \
    _Pragma("unroll")                                                          \
    for (int p = 0; p < 16; p++) {                                             \
        const int g = p >> 2, sub = p & 3;                                     \
        const int colg = g * 256 + jH * 64 + sub * 16;                         \
        u16 tmp[16];                                                           \
        if (isf32) {                                                           \
            const float* s = (const float*)(Wsrc) + (size_t)tid * 1024 + colg; \
            _Pragma("unroll")                                                  \
            for (int c = 0; c < 16; c++) tmp[c] = f2bf(s[c]);                  \
        } else {                                                               \
            const u16* s = (const u16*)(Wsrc) + (size_t)tid * 1024 + colg;     \
            *(uint4*)&tmp[0] = *(const uint4*)s;                               \
            *(uint4*)&tmp[8] = *(const uint4*)(s + 8);                         \
        }                                                                      \
        __syncthreads(); /* previous piece fully read */                       \
        _Pragma("unroll")                                                      \
        for (int c = 0; c < 16; c++) hs[c * 264 + tid] = tmp[c];               \
        __syncthreads();                                                       \
        if (sub == w) {                                                        \
            _Pragma("unroll")                                                  \
            for (int ks = 0; ks < 8; ks++)                                     \
                (Bf)[g][ks] = *(const short8*)&hs[n16 * 264 + ks * 32 + q * 8];\
        }                                                                      \
    }

    PRELOAD_W(Wh, Bh)
    PRELOAD_W(Wx, Bx)
    __syncthreads();

// x A-fragment loader for timestep t (batch row b0+n16): dtype-adaptive
#define LOADX(t, dst)                                                              \
    if (isf32) {                                                                   \
        const float* xb = (const float*)x + ((size_t)(b0 + n16) * 2048 + (t)) * 256 + q * 8; \
        _Pragma("unroll")                                                          \
        for (int ks = 0; ks < 8; ks++) {                                           \
            u16 tmp[8];                                                            \
            _Pragma("unroll")                                                      \
            for (int j = 0; j < 8; j++) tmp[j] = f2bf(xb[ks * 32 + j]);            \
            (dst)[ks] = *(const short8*)tmp;                                       \
        }                                                                          \
    } else {                                                                       \
        const u16* xb = (const u16*)x + ((size_t)(b0 + n16) * 2048 + (t)) * 256 + q * 8; \
        _Pragma("unroll")                                                          \
        for (int ks = 0; ks < 8; ks++) (dst)[ks] = *(const short8*)(xb + ks * 32); \
    }

    // ---- per-lane constants / state (dtype-adaptive reads) ----
    float bv[4];
#pragma unroll
    for (int g = 0; g < 4; g++)
        bv[g] = isf32 ? ((const float*)bias)[g * 256 + hc]
                      : bf2f(((const u16*)bias)[g * 256 + hc]);

    float creg[4];
#pragma unroll
    for (int r = 0; r < 4; r++)
        creg[r] = isf32 ? ((const float*)c0)[(size_t)(bq + r) * 256 + hc]
                        : bf2f(((const u16*)c0)[(size_t)(bq + r) * 256 + hc]);

    // ---- stage h_{-1} = h0 straight from global into LDS: hs[m][k=tid] ----
#pragma unroll
    for (int m = 0; m < 16; m++) {
        u16 v = isf32 ? f2bf(((const float*)h0)[(size_t)(b0 + m) * 256 + tid])
                      : ((const u16*)h0)[(size_t)(b0 + m) * 256 + tid];
        hs[m * 264 + tid] = v;
    }

    // ---- zx for t=0: x[t=0] @ Wx + b ----
    f32x4 zx[4];
    {
        short8 xf[8];
        LOADX(0, xf)
#pragma unroll
        for (int g = 0; g < 4; g++) { f32x4 a = {bv[g], bv[g], bv[g], bv[g]}; zx[g] = a; }
#pragma unroll
        for (int ks = 0; ks < 8; ks++)
#pragma unroll
            for (int g = 0; g < 4; g++)
                zx[g] = __builtin_amdgcn_mfma_f32_16x16x32_bf16(xf[ks], Bx[g][ks], zx[g], 0, 0, 0);
    }

    // dead-latch: once a sync guard trips, never spin again (bounded worst case;
    // output will be wrong -> verification failure, NOT a harness hang).
    int dead = 0;

    // ---- sequential scan: 2048 steps ----
    for (int tl = 0; tl < 2048; tl++) {
        // 0. issue x prefetch for t+1 (independent of h; lands during spin)
        short8 xfn[8];
        if (tl + 1 < 2048) { LOADX(tl + 1, xfn) }

        if (tl > 0) {
            // 1. wait for all 4 WGs' step tl-1 arrivals (monotonic ctr = 4*tl)
            const int target = 4 * tl;
            if (!dead) {
                int guard = 0;
                if (fast) {
                    while (xcd_load_i32(ctrp) < target) {
                        __builtin_amdgcn_s_sleep(1);
                        if (++guard > (1 << 20)) { dead = 1; break; }
                    }
                } else {
                    while (__hip_atomic_load(ctrp, __ATOMIC_ACQUIRE, AGENT) < target) {
                        __builtin_amdgcn_s_sleep(1);
                        if (++guard > (1 << 20)) { dead = 1; break; }
                    }
                }
            }
            // 2. stage h_{t-1} -> LDS hs[m][k]; thread tid owns column hc=tid
            const int par = (tl & 1) ^ 1;
            const u16* hp = hgrp + par * 4096 + tid * 16;
            u32 hv[8];
            if (fast) {
                xcd_load_32B(hp, hv);
            } else {
                const u32* hp32 = (const u32*)hp;
#pragma unroll
                for (int i2 = 0; i2 < 8; i2++) hv[i2] = __hip_atomic_load(hp32 + i2, __ATOMIC_RELAXED, AGENT);
            }
#pragma unroll
            for (int m = 0; m < 16; m++) {
                u16 val = (u16)((hv[m >> 1] >> ((m & 1) * 16)) & 0xFFFFu);
                hs[m * 264 + tid] = val;
            }
        }
        __syncthreads();  // hs visible to all waves (also covers pre-loop h0 staging)

        // 3. z = zx + h @ Wh
        f32x4 acc[4];
#pragma unroll
        for (int g = 0; g < 4; g++) acc[g] = zx[g];
#pragma unroll
        for (int ks = 0; ks < 8; ks++) {
            short8 af = *(const short8*)&hs[n16 * 264 + ks * 32 + q * 8];
#pragma unroll
            for (int g = 0; g < 4; g++)
                acc[g] = __builtin_amdgcn_mfma_f32_16x16x32_bf16(af, Bh[g][ks], acc[g], 0, 0, 0);
        }

        // 4. gates + state update; publish h (bf16), then arrive
        float hf[4];
        u16 hb[4];
#pragma unroll
        for (int r = 0; r < 4; r++) {
            float ig = sigmoidf_(acc[0][r]);
            float fg = sigmoidf_(acc[1][r]);
            float gg = tanhf_(acc[2][r]);
            float og = sigmoidf_(acc[3][r]);
            float cn = fg * creg[r] + ig * gg;
            creg[r] = cn;
            hf[r] = og * tanhf_(cn);
            hb[r] = f2bf(hf[r]);
        }
        {
            const int par = tl & 1;
            u32* hp = (u32*)(hgrp + par * 4096 + hc * 16 + q * 4);
            u32 lo = (u32)hb[0] | ((u32)hb[1] << 16);
            u32 hi = (u32)hb[2] | ((u32)hb[3] << 16);
            if (fast) {
                hp[0] = lo;  // plain stores: land in the XCD L2; syncthreads drains vmcnt
                hp[1] = hi;
            } else {
                __hip_atomic_store(hp + 0, lo, __ATOMIC_RELAXED, AGENT);
                __hip_atomic_store(hp + 1, hi, __ATOMIC_RELAXED, AGENT);
            }
        }
        __syncthreads();  // all waves' hbuf stores drained (vmcnt0) before the arrival add
        if (tid == 0) {
            if (fast) xcd_atomic_add(ctrp, 1);  // RMW executes at local L2 (hot line)
            else __hip_atomic_fetch_add(ctrp, 1, __ATOMIC_RELEASE, AGENT);
        }

        // 5. off-critical-path: out stores + zx for next step
#pragma unroll
        for (int r = 0; r < 4; r++) {
            size_t oi = ((size_t)(bq + r) * 2048 + tl) * 256 + hc;
            if (isf32) ((float*)out)[oi] = hf[r];
            else       ((u16*)out)[oi] = hb[r];
        }

        if (tl + 1 < 2048) {
#pragma unroll
            for (int g = 0; g < 4; g++) { f32x4 a = {bv[g], bv[g], bv[g], bv[g]}; zx[g] = a; }
#pragma unroll
            for (int ks = 0; ks < 8; ks++)
#pragma unroll
                for (int g = 0; g < 4; g++)
                    zx[g] = __builtin_amdgcn_mfma_f32_16x16x32_bf16(xfn[ks], Bx[g][ks], zx[g], 0, 0, 0);
        }
    }
}

// =====================================================================
extern "C" void kernel_launch(void* const* d_in, const int* in_sizes, int n_in,
                              void* d_out, int out_size, void* d_ws, size_t ws_size,
                              hipStream_t stream) {
    const void* x    = d_in[0];
    const void* Wx   = d_in[1];
    const void* Wh   = d_in[2];
    const void* bias = d_in[3];
    const void* h0   = d_in[4];
    const void* c0   = d_in[5];

    // ws layout: hbuf (4 groups * 2 par * 256 hc * 16 b u16 = 64KB) | 512-int control block
    u16* hbuf = (u16*)d_ws;
    int* ints = (int*)((char*)d_ws + 65536);

    lstm_init<<<1, 256, 0, stream>>>((const u16*)x, ints);
    lstm_fused<<<256, 256, 0, stream>>>(x, Wx, Wh, bias, c0, h0, hbuf, d_out, ints);
}